// Round 1
// baseline (455.681 us; speedup 1.0000x reference)
//
#include <hip/hip_runtime.h>

typedef __bf16 bf16x8 __attribute__((ext_vector_type(8)));
typedef float  f32x4  __attribute__((ext_vector_type(4)));

#define KDIM  4096
#define NDIM  4096
#define REDIN 2048

static __device__ __forceinline__ unsigned short f2bf(float f) {
    return __builtin_bit_cast(unsigned short, (__bf16)f);
}

// 128x128 output tile per block, BK=32 (one weight rotation block per K-step).
// 4 waves in 2x2, each wave computes a 64x64 sub-tile via 4x4 frags of 16x16x32 MFMA.
__global__ __launch_bounds__(256, 2)
void ssl_gemm(const float* __restrict__ x, const float* __restrict__ w,
              const float* __restrict__ bias, const int* __restrict__ rn,
              float* __restrict__ out)
{
    // +8 ushort pad -> row stride 80B (20 banks): breaks power-of-2 conflicts,
    // keeps 16B alignment for ds_read_b128 (80 % 16 == 0).
    __shared__ __align__(16) unsigned short As[128][40];
    __shared__ __align__(16) unsigned short Bs[128][40];

    const int R0 = rn[0], R1 = rn[1], R2 = rn[2], R3 = rn[3];

    const int tid = threadIdx.x;
    const int n0 = blockIdx.x * 128;   // N-tile base
    const int m0 = blockIdx.y * 128;   // M-tile base

    // staging decomposition: 8 threads cover one 32-float row segment (float4 each)
    const int srow = tid >> 3;         // 0..31
    const int scol = (tid & 7) * 4;    // 0,4,...,28

    const int lane = tid & 63;
    const int wid  = tid >> 6;
    const int wr   = wid >> 1;         // wave row (0..1)
    const int wc   = wid & 1;          // wave col (0..1)
    const int lrow = lane & 15;
    const int lk   = (lane >> 4) * 8;  // k sub-offset within BK=32

    f32x4 acc[4][4];
#pragma unroll
    for (int m = 0; m < 4; ++m)
#pragma unroll
        for (int n = 0; n < 4; ++n)
            acc[m][n] = (f32x4)(0.0f);

    for (int i = 0; i < KDIM / 32; ++i) {
        const int it   = i >> 1;
        const int itin = i & 1;
        const int k0   = i * 32;

        // ---- stage A: x[m0+row, k0 + 0..31] -> bf16 As[row][k] ----
#pragma unroll
        for (int p = 0; p < 4; ++p) {
            const int row = p * 32 + srow;
            const float4 v = *(const float4*)(x + (size_t)(m0 + row) * KDIM + k0 + scol);
            ushort4 s;
            s.x = f2bf(v.x); s.y = f2bf(v.y); s.z = f2bf(v.z); s.w = f2bf(v.w);
            *(ushort4*)&As[row][scol] = s;   // 8B store, aligned (80%8==0, scol*2%8==0)
        }

        // ---- stage B: weight[n, it*32 + c] -> Bs[n_local][(c - off) & 31] ----
        const int hbase = R3 + R1 * (it + 1) + R0 * (itin + 1);
#pragma unroll
        for (int p = 0; p < 4; ++p) {
            const int nl = p * 32 + srow;
            const int j  = (n0 + nl) >> 5;                 // global N-block
            const int hh = hbase + R2 * j;
            const int off = 32 - ((hh << 2) & 31);         // in {4..32}
            const float4 v = *(const float4*)(w + (size_t)(n0 + nl) * REDIN + it * 32 + scol);
            Bs[nl][(scol + 0 - off) & 31] = f2bf(v.x);
            Bs[nl][(scol + 1 - off) & 31] = f2bf(v.y);
            Bs[nl][(scol + 2 - off) & 31] = f2bf(v.z);
            Bs[nl][(scol + 3 - off) & 31] = f2bf(v.w);
        }

        __syncthreads();

        // ---- compute: 4 A-frags x 4 B-frags, 16 MFMAs ----
        bf16x8 af[4], bfr[4];
#pragma unroll
        for (int m = 0; m < 4; ++m)
            af[m] = *(const bf16x8*)&As[wr * 64 + m * 16 + lrow][lk];
#pragma unroll
        for (int n = 0; n < 4; ++n)
            bfr[n] = *(const bf16x8*)&Bs[wc * 64 + n * 16 + lrow][lk];

#pragma unroll
        for (int m = 0; m < 4; ++m)
#pragma unroll
            for (int n = 0; n < 4; ++n)
                acc[m][n] = __builtin_amdgcn_mfma_f32_16x16x32_bf16(af[m], bfr[n], acc[m][n], 0, 0, 0);

        __syncthreads();
    }

    // ---- epilogue: C/D layout col=lane&15, row=(lane>>4)*4+e ----
#pragma unroll
    for (int n = 0; n < 4; ++n) {
        const int col = n0 + wc * 64 + n * 16 + lrow;
        const float bv = bias[col];
#pragma unroll
        for (int m = 0; m < 4; ++m) {
            const int rbase = m0 + wr * 64 + m * 16 + (lane >> 4) * 4;
#pragma unroll
            for (int e = 0; e < 4; ++e) {
                out[(size_t)(rbase + e) * NDIM + col] = acc[m][n][e] + bv;
            }
        }
    }
}

extern "C" void kernel_launch(void* const* d_in, const int* in_sizes, int n_in,
                              void* d_out, int out_size, void* d_ws, size_t ws_size,
                              hipStream_t stream) {
    const float* x    = (const float*)d_in[0];
    const float* wgt  = (const float*)d_in[1];
    const float* bias = (const float*)d_in[2];
    const int*   rn   = (const int*)d_in[3];
    float* out = (float*)d_out;

    const int M = in_sizes[0] / KDIM;          // 8192
    dim3 grid(NDIM / 128, M / 128);            // 32 x 64
    ssl_gemm<<<grid, dim3(256), 0, stream>>>(x, wgt, bias, rn, out);
}

// Round 2
// 377.544 us; speedup vs baseline: 1.2070x; 1.2070x over previous
//
#include <hip/hip_runtime.h>

typedef __bf16 bf16x8 __attribute__((ext_vector_type(8)));
typedef float  f32x4  __attribute__((ext_vector_type(4)));
typedef unsigned short ushort8 __attribute__((ext_vector_type(8)));

#define KDIM  4096
#define NDIM  4096
#define REDIN 2048

static __device__ __forceinline__ unsigned short f2bf(float f) {
    return __builtin_bit_cast(unsigned short, (__bf16)f);
}

typedef __attribute__((address_space(3))) void       lds_void;
typedef const __attribute__((address_space(1))) void gbl_cvoid;

static __device__ __forceinline__ void gload16(const void* g, void* l) {
    __builtin_amdgcn_global_load_lds((gbl_cvoid*)g, (lds_void*)l, 16, 0, 0);
}

// ---------------- prep 1: x fp32 -> bf16 [M][K] ----------------
__global__ void cvt_x(const float* __restrict__ x, unsigned short* __restrict__ xb,
                      long n8) {
    long idx = (long)blockIdx.x * blockDim.x + threadIdx.x;
    long stride = (long)gridDim.x * blockDim.x;
    for (long i = idx; i < n8; i += stride) {
        const float4 a = ((const float4*)x)[2 * i];
        const float4 b = ((const float4*)x)[2 * i + 1];
        ushort8 s;
        s[0] = f2bf(a.x); s[1] = f2bf(a.y); s[2] = f2bf(a.z); s[3] = f2bf(a.w);
        s[4] = f2bf(b.x); s[5] = f2bf(b.y); s[6] = f2bf(b.z); s[7] = f2bf(b.w);
        ((ushort8*)xb)[i] = s;
    }
}

// ---------------- prep 2: weight -> rotation-expanded bf16 [N][K] ----------------
// Wexp[n][i*32+kk] = bf16( w[n][it*32 + ((kk + off(i, n>>5)) & 31)] )
__global__ void expand_w(const float* __restrict__ w, unsigned short* __restrict__ wx,
                         const int* __restrict__ rn) {
    const int R0 = rn[0], R1 = rn[1], R2 = rn[2], R3 = rn[3];
    const long total = (long)NDIM * (KDIM / 8);
    long idx = (long)blockIdx.x * blockDim.x + threadIdx.x;
    long stride = (long)gridDim.x * blockDim.x;
    for (long t = idx; t < total; t += stride) {
        const int kp = (int)(t & (KDIM / 8 - 1));   // 0..511
        const int n  = (int)(t >> 9);
        const int k0 = kp * 8;
        const int i  = k0 >> 5;
        const int kk0 = k0 & 31;
        const int it = i >> 1;
        const int h  = R3 + R2 * (n >> 5) + R1 * (it + 1) + R0 * ((i & 1) + 1);
        const int off = 32 - ((h << 2) & 31);
        const float* src = w + (long)n * REDIN + it * 32;
        ushort8 s;
#pragma unroll
        for (int q = 0; q < 8; ++q)
            s[q] = f2bf(src[(kk0 + q + off) & 31]);
        ((ushort8*)wx)[t] = s;
    }
}

// ---------------- main GEMM: m97 structure, 128x128 tile, BK=32 ----------------
__global__ __launch_bounds__(256, 2)
void gemm_bt(const unsigned short* __restrict__ A,   // bf16 [M][K]
             const unsigned short* __restrict__ B,   // bf16 [N][K]
             const float* __restrict__ bias,
             float* __restrict__ out, int M)
{
    __shared__ __align__(16) unsigned short As[128 * 32];
    __shared__ __align__(16) unsigned short Bs[128 * 32];

    // XCD-aware bijective swizzle: nwg = 32*(M/128) divisible by 8.
    const int nwg = gridDim.x;
    const int cpx = nwg >> 3;
    const int orig = blockIdx.x;
    const int swz = (orig & 7) * cpx + (orig >> 3);
    const int n0 = (swz & 31) * 128;       // n-tile fastest: neighbors share A-panel
    const int m0 = (swz >> 5) * 128;

    const int tid  = threadIdx.x;
    const int lane = tid & 63;
    const int wid  = tid >> 6;
    const int wr   = wid >> 1;
    const int wc   = wid & 1;
    const int lrow = lane & 15;
    const int lk   = (lane >> 4) * 8;

    // staging: thread t covers 16B at LDS offset t*16 (wave-uniform + lane*16)
    const int srow = tid >> 2;             // 0..63
    const int scol = (tid & 3) * 8;        // element offset in row (8 bf16 = 16B)

    const unsigned short* Abase0 = A + (long)(m0 + srow) * KDIM + scol;
    const unsigned short* Abase1 = A + (long)(m0 + 64 + srow) * KDIM + scol;
    const unsigned short* Bbase0 = B + (long)(n0 + srow) * KDIM + scol;
    const unsigned short* Bbase1 = B + (long)(n0 + 64 + srow) * KDIM + scol;

    f32x4 acc[4][4];
#pragma unroll
    for (int m = 0; m < 4; ++m)
#pragma unroll
        for (int n = 0; n < 4; ++n)
            acc[m][n] = (f32x4)(0.0f);

    for (int i = 0; i < KDIM / 32; ++i) {
        const int k0 = i * 32;
        gload16(Abase0 + k0, &As[tid * 8]);
        gload16(Abase1 + k0, &As[2048 + tid * 8]);
        gload16(Bbase0 + k0, &Bs[tid * 8]);
        gload16(Bbase1 + k0, &Bs[2048 + tid * 8]);
        __syncthreads();

        bf16x8 af[4], bfr[4];
#pragma unroll
        for (int m = 0; m < 4; ++m)
            af[m] = *(const bf16x8*)&As[(wr * 64 + m * 16 + lrow) * 32 + lk];
#pragma unroll
        for (int n = 0; n < 4; ++n)
            bfr[n] = *(const bf16x8*)&Bs[(wc * 64 + n * 16 + lrow) * 32 + lk];

#pragma unroll
        for (int m = 0; m < 4; ++m)
#pragma unroll
            for (int n = 0; n < 4; ++n)
                acc[m][n] = __builtin_amdgcn_mfma_f32_16x16x32_bf16(af[m], bfr[n], acc[m][n], 0, 0, 0);

        __syncthreads();
    }

#pragma unroll
    for (int n = 0; n < 4; ++n) {
        const int col = n0 + wc * 64 + n * 16 + lrow;
        const float bv = bias[col];
#pragma unroll
        for (int m = 0; m < 4; ++m) {
            const long rbase = m0 + wr * 64 + m * 16 + (lane >> 4) * 4;
#pragma unroll
            for (int e = 0; e < 4; ++e)
                out[(rbase + e) * NDIM + col] = acc[m][n][e] + bv;
        }
    }
}

// ---------------- fallback (round-0 fused kernel) for small ws ----------------
__global__ __launch_bounds__(256, 2)
void ssl_gemm_fused(const float* __restrict__ x, const float* __restrict__ w,
                    const float* __restrict__ bias, const int* __restrict__ rn,
                    float* __restrict__ out)
{
    __shared__ __align__(16) unsigned short As[128][40];
    __shared__ __align__(16) unsigned short Bs[128][40];

    const int R0 = rn[0], R1 = rn[1], R2 = rn[2], R3 = rn[3];
    const int tid = threadIdx.x;
    const int n0 = blockIdx.x * 128;
    const int m0 = blockIdx.y * 128;
    const int srow = tid >> 3;
    const int scol = (tid & 7) * 4;
    const int lane = tid & 63;
    const int wid  = tid >> 6;
    const int wr   = wid >> 1;
    const int wc   = wid & 1;
    const int lrow = lane & 15;
    const int lk   = (lane >> 4) * 8;

    f32x4 acc[4][4];
#pragma unroll
    for (int m = 0; m < 4; ++m)
#pragma unroll
        for (int n = 0; n < 4; ++n)
            acc[m][n] = (f32x4)(0.0f);

    for (int i = 0; i < KDIM / 32; ++i) {
        const int it   = i >> 1;
        const int k0   = i * 32;
#pragma unroll
        for (int p = 0; p < 4; ++p) {
            const int row = p * 32 + srow;
            const float4 v = *(const float4*)(x + (size_t)(m0 + row) * KDIM + k0 + scol);
            ushort4 s;
            s.x = f2bf(v.x); s.y = f2bf(v.y); s.z = f2bf(v.z); s.w = f2bf(v.w);
            *(ushort4*)&As[row][scol] = s;
        }
        const int hbase = R3 + R1 * (it + 1) + R0 * ((i & 1) + 1);
#pragma unroll
        for (int p = 0; p < 4; ++p) {
            const int nl = p * 32 + srow;
            const int j  = (n0 + nl) >> 5;
            const int off = 32 - (((hbase + R2 * j) << 2) & 31);
            const float4 v = *(const float4*)(w + (size_t)(n0 + nl) * REDIN + it * 32 + scol);
            Bs[nl][(scol + 0 - off) & 31] = f2bf(v.x);
            Bs[nl][(scol + 1 - off) & 31] = f2bf(v.y);
            Bs[nl][(scol + 2 - off) & 31] = f2bf(v.z);
            Bs[nl][(scol + 3 - off) & 31] = f2bf(v.w);
        }
        __syncthreads();

        bf16x8 af[4], bfr[4];
#pragma unroll
        for (int m = 0; m < 4; ++m)
            af[m] = *(const bf16x8*)&As[wr * 64 + m * 16 + lrow][lk];
#pragma unroll
        for (int n = 0; n < 4; ++n)
            bfr[n] = *(const bf16x8*)&Bs[wc * 64 + n * 16 + lrow][lk];
#pragma unroll
        for (int m = 0; m < 4; ++m)
#pragma unroll
            for (int n = 0; n < 4; ++n)
                acc[m][n] = __builtin_amdgcn_mfma_f32_16x16x32_bf16(af[m], bfr[n], acc[m][n], 0, 0, 0);
        __syncthreads();
    }

#pragma unroll
    for (int n = 0; n < 4; ++n) {
        const int col = n0 + wc * 64 + n * 16 + lrow;
        const float bv = bias[col];
#pragma unroll
        for (int m = 0; m < 4; ++m) {
            const int rbase = m0 + wr * 64 + m * 16 + (lane >> 4) * 4;
#pragma unroll
            for (int e = 0; e < 4; ++e)
                out[(size_t)(rbase + e) * NDIM + col] = acc[m][n][e] + bv;
        }
    }
}

extern "C" void kernel_launch(void* const* d_in, const int* in_sizes, int n_in,
                              void* d_out, int out_size, void* d_ws, size_t ws_size,
                              hipStream_t stream) {
    const float* x    = (const float*)d_in[0];
    const float* wgt  = (const float*)d_in[1];
    const float* bias = (const float*)d_in[2];
    const int*   rn   = (const int*)d_in[3];
    float* out = (float*)d_out;

    const int M = in_sizes[0] / KDIM;                       // 8192
    const size_t need = ((size_t)M * KDIM + (size_t)NDIM * KDIM) * sizeof(unsigned short);

    if (ws_size >= need) {
        unsigned short* xb = (unsigned short*)d_ws;
        unsigned short* wx = xb + (size_t)M * KDIM;

        cvt_x<<<2048, 256, 0, stream>>>(x, xb, (long)M * KDIM / 8);
        expand_w<<<2048, 256, 0, stream>>>(wgt, wx, rn);

        const int nwg = (NDIM / 128) * (M / 128);           // 2048
        gemm_bt<<<nwg, 256, 0, stream>>>(xb, wx, bias, out, M);
    } else {
        dim3 grid(NDIM / 128, M / 128);
        ssl_gemm_fused<<<grid, dim3(256), 0, stream>>>(x, wgt, bias, rn, out);
    }
}

// Round 3
// 324.993 us; speedup vs baseline: 1.4021x; 1.1617x over previous
//
#include <hip/hip_runtime.h>

typedef __bf16 bf16x8 __attribute__((ext_vector_type(8)));
typedef float  f32x4  __attribute__((ext_vector_type(4)));
typedef unsigned short ushort8 __attribute__((ext_vector_type(8)));

#define KDIM  4096
#define NDIM  4096
#define REDIN 2048

static __device__ __forceinline__ unsigned short f2bf(float f) {
    return __builtin_bit_cast(unsigned short, (__bf16)f);
}

typedef __attribute__((address_space(3))) void       lds_void;
typedef const __attribute__((address_space(1))) void gbl_cvoid;

static __device__ __forceinline__ void gload16(const void* g, void* l) {
    __builtin_amdgcn_global_load_lds((gbl_cvoid*)g, (lds_void*)l, 16, 0, 0);
}

// ---------------- prep 1: x fp32 -> bf16 [M][K] ----------------
__global__ void cvt_x(const float* __restrict__ x, unsigned short* __restrict__ xb,
                      long n8) {
    long idx = (long)blockIdx.x * blockDim.x + threadIdx.x;
    long stride = (long)gridDim.x * blockDim.x;
    for (long i = idx; i < n8; i += stride) {
        const float4 a = ((const float4*)x)[2 * i];
        const float4 b = ((const float4*)x)[2 * i + 1];
        ushort8 s;
        s[0] = f2bf(a.x); s[1] = f2bf(a.y); s[2] = f2bf(a.z); s[3] = f2bf(a.w);
        s[4] = f2bf(b.x); s[5] = f2bf(b.y); s[6] = f2bf(b.z); s[7] = f2bf(b.w);
        ((ushort8*)xb)[i] = s;
    }
}

// ---------------- prep 2: weight -> rotation-expanded bf16 [N][K] ----------------
__global__ void expand_w(const float* __restrict__ w, unsigned short* __restrict__ wx,
                         const int* __restrict__ rn) {
    const int R0 = rn[0], R1 = rn[1], R2 = rn[2], R3 = rn[3];
    const long total = (long)NDIM * (KDIM / 8);
    long idx = (long)blockIdx.x * blockDim.x + threadIdx.x;
    long stride = (long)gridDim.x * blockDim.x;
    for (long t = idx; t < total; t += stride) {
        const int kp = (int)(t & (KDIM / 8 - 1));
        const int n  = (int)(t >> 9);
        const int k0 = kp * 8;
        const int i  = k0 >> 5;
        const int kk0 = k0 & 31;
        const int it = i >> 1;
        const int h  = R3 + R2 * (n >> 5) + R1 * (it + 1) + R0 * ((i & 1) + 1);
        const int off = 32 - ((h << 2) & 31);
        const float* src = w + (long)n * REDIN + it * 32;
        ushort8 s;
#pragma unroll
        for (int q = 0; q < 8; ++q)
            s[q] = f2bf(src[(kk0 + q + off) & 31]);
        ((ushort8*)wx)[t] = s;
    }
}

// ---------------- main GEMM: 256x256 tile, BK=32, 4-deep ring, counted vmcnt ----------------
// LDS swizzle: logical (row, 16B-slot sl) stored at slot sl ^ ((row>>1)&3).
// Staged with linear dest + inverse-swizzled global source; read with swizzled addr.

#define STAGE_T(T)                                                          \
  {                                                                         \
    const int _b  = (T) & 3;                                                \
    const long _ko = (long)(T) * 32;                                        \
    gload16(srcA1 + _ko, ldsA + _b * 8192 + dst1);                          \
    gload16(srcA2 + _ko, ldsA + _b * 8192 + dst2);                          \
    gload16(srcB1 + _ko, ldsB + _b * 8192 + dst1);                          \
    gload16(srcB2 + _ko, ldsB + _b * 8192 + dst2);                          \
  }

#define KBODY(T, CUR, NXT, DOSTAGE, VMSTR)                                  \
  {                                                                         \
    if (DOSTAGE) STAGE_T((T) + 3);                                          \
    asm volatile("s_waitcnt vmcnt(" VMSTR ")" ::: "memory");                \
    __builtin_amdgcn_sched_barrier(0);                                      \
    __builtin_amdgcn_s_barrier();                                           \
    __builtin_amdgcn_sched_barrier(0);                                      \
    const char* _pa = (const char*)ldsA + ((T) & 3) * 16384 + aOff;         \
    const char* _pb = (const char*)ldsB + (((T) + 1) & 3) * 16384 + bOff;   \
    _Pragma("unroll")                                                       \
    for (int _n = 0; _n < 4; ++_n)                                          \
      bf##NXT[_n] = *(const bf16x8*)(_pb + _n * 1024);                      \
    _Pragma("unroll")                                                       \
    for (int _m = 0; _m < 8; ++_m)                                          \
      af[_m] = *(const bf16x8*)(_pa + _m * 1024);                           \
    _Pragma("unroll")                                                       \
    for (int _m = 0; _m < 8; ++_m)                                          \
      _Pragma("unroll")                                                     \
      for (int _n = 0; _n < 4; ++_n)                                        \
        acc[_m][_n] = __builtin_amdgcn_mfma_f32_16x16x32_bf16(              \
            af[_m], bf##CUR[_n], acc[_m][_n], 0, 0, 0);                     \
    asm volatile("s_waitcnt lgkmcnt(0)" ::: "memory");                      \
    __builtin_amdgcn_sched_barrier(0);                                      \
    __builtin_amdgcn_s_barrier();                                           \
  }

__global__ __launch_bounds__(512, 2)
void gemm_bt256(const unsigned short* __restrict__ A,   // bf16 [M][K]
                const unsigned short* __restrict__ B,   // bf16 [N][K]
                const float* __restrict__ bias,
                float* __restrict__ out, int M)
{
    __shared__ __align__(16) unsigned short ldsA[4 * 8192];   // 64 KB
    __shared__ __align__(16) unsigned short ldsB[4 * 8192];   // 64 KB

    // XCD-aware bijective swizzle (nwg % 8 == 0 here: (M/256)*16)
    const int nwg = gridDim.x;
    const int bid = blockIdx.x;
    int swzb = bid;
    if ((nwg & 7) == 0) {
        const int cpx = nwg >> 3;
        swzb = (bid & 7) * cpx + (bid >> 3);
    }
    const int ntn = NDIM / 256;                 // 16
    const int n0 = (swzb % ntn) * 256;
    const int m0 = (swzb / ntn) * 256;

    const int tid  = threadIdx.x;
    const int lane = tid & 63;
    const int wid  = tid >> 6;
    const int wr   = wid >> 2;                  // 0..1
    const int wc   = wid & 3;                   // 0..3
    const int lrow = lane & 15;

    // ---- staging addressing (linear LDS dest, inverse-swizzled source) ----
    const int sswz = (tid & 3) ^ ((tid >> 3) & 3);
    const int dst1 = tid * 8;                   // ushort units (16B per thread)
    const int dst2 = tid * 8 + 4096;
    const unsigned short* srcA1 = A + (size_t)(m0 + (tid >> 2)) * KDIM + 8 * sswz;
    const unsigned short* srcA2 = srcA1 + (size_t)128 * KDIM;
    const unsigned short* srcB1 = B + (size_t)(n0 + (tid >> 2)) * KDIM + 8 * sswz;
    const unsigned short* srcB2 = srcB1 + (size_t)128 * KDIM;

    // ---- frag read addressing (swizzled) ----
    const int rswz = (lane >> 4) ^ ((lane >> 1) & 3);
    const int aOff = (wr * 128 + lrow) * 64 + (rswz << 4);   // bytes
    const int bOff = (wc * 64 + lrow) * 64 + (rswz << 4);    // bytes

    f32x4 acc[8][4];
#pragma unroll
    for (int m = 0; m < 8; ++m)
#pragma unroll
        for (int n = 0; n < 4; ++n)
            acc[m][n] = (f32x4)(0.0f);

    bf16x8 af[8], bfA[4], bfB[4];

    // ---- prologue: stage tiles 0,1,2; load bfA = tile 0 B-frags ----
    STAGE_T(0);
    STAGE_T(1);
    STAGE_T(2);
    asm volatile("s_waitcnt vmcnt(8)" ::: "memory");   // tile 0 landed
    __builtin_amdgcn_sched_barrier(0);
    __builtin_amdgcn_s_barrier();
    __builtin_amdgcn_sched_barrier(0);
    {
        const char* _pb = (const char*)ldsB + bOff;    // buf 0
#pragma unroll
        for (int n = 0; n < 4; ++n)
            bfA[n] = *(const bf16x8*)(_pb + n * 1024);
    }

    // ---- main loop: tiles 0..123 (ping-pong on B-frags) ----
    for (int tt = 0; tt < 124; tt += 2) {
        KBODY(tt,     A, B, true, "8");
        KBODY(tt + 1, B, A, true, "8");
    }
    // ---- tail ----
    KBODY(124, A, B, true,  "8");   // stages tile 127
    KBODY(125, B, A, false, "4");
    KBODY(126, A, B, false, "0");
    // t = 127: MFMA only
    {
        const char* _pa = (const char*)ldsA + 3 * 16384 + aOff;
#pragma unroll
        for (int m = 0; m < 8; ++m)
            af[m] = *(const bf16x8*)(_pa + m * 1024);
#pragma unroll
        for (int m = 0; m < 8; ++m)
#pragma unroll
            for (int n = 0; n < 4; ++n)
                acc[m][n] = __builtin_amdgcn_mfma_f32_16x16x32_bf16(
                    af[m], bfB[n], acc[m][n], 0, 0, 0);
    }

    // ---- epilogue ----
#pragma unroll
    for (int n = 0; n < 4; ++n) {
        const int col = n0 + wc * 64 + n * 16 + lrow;
        const float bv = bias[col];
#pragma unroll
        for (int m = 0; m < 8; ++m) {
            const size_t rbase = (size_t)(m0 + wr * 128 + m * 16 + (lane >> 4) * 4);
#pragma unroll
            for (int e = 0; e < 4; ++e)
                out[(rbase + e) * NDIM + col] = acc[m][n][e] + bv;
        }
    }
}

// ---------------- fallback (fused) for small ws ----------------
__global__ __launch_bounds__(256, 2)
void ssl_gemm_fused(const float* __restrict__ x, const float* __restrict__ w,
                    const float* __restrict__ bias, const int* __restrict__ rn,
                    float* __restrict__ out)
{
    __shared__ __align__(16) unsigned short As[128][40];
    __shared__ __align__(16) unsigned short Bs[128][40];

    const int R0 = rn[0], R1 = rn[1], R2 = rn[2], R3 = rn[3];
    const int tid = threadIdx.x;
    const int n0 = blockIdx.x * 128;
    const int m0 = blockIdx.y * 128;
    const int srow = tid >> 3;
    const int scol = (tid & 7) * 4;
    const int lane = tid & 63;
    const int wid  = tid >> 6;
    const int wr   = wid >> 1;
    const int wc   = wid & 1;
    const int lrow = lane & 15;
    const int lk   = (lane >> 4) * 8;

    f32x4 acc[4][4];
#pragma unroll
    for (int m = 0; m < 4; ++m)
#pragma unroll
        for (int n = 0; n < 4; ++n)
            acc[m][n] = (f32x4)(0.0f);

    for (int i = 0; i < KDIM / 32; ++i) {
        const int it   = i >> 1;
        const int k0   = i * 32;
#pragma unroll
        for (int p = 0; p < 4; ++p) {
            const int row = p * 32 + srow;
            const float4 v = *(const float4*)(x + (size_t)(m0 + row) * KDIM + k0 + scol);
            ushort4 s;
            s.x = f2bf(v.x); s.y = f2bf(v.y); s.z = f2bf(v.z); s.w = f2bf(v.w);
            *(ushort4*)&As[row][scol] = s;
        }
        const int hbase = R3 + R1 * (it + 1) + R0 * ((i & 1) + 1);
#pragma unroll
        for (int p = 0; p < 4; ++p) {
            const int nl = p * 32 + srow;
            const int j  = (n0 + nl) >> 5;
            const int off = 32 - (((hbase + R2 * j) << 2) & 31);
            const float4 v = *(const float4*)(w + (size_t)(n0 + nl) * REDIN + it * 32 + scol);
            Bs[nl][(scol + 0 - off) & 31] = f2bf(v.x);
            Bs[nl][(scol + 1 - off) & 31] = f2bf(v.y);
            Bs[nl][(scol + 2 - off) & 31] = f2bf(v.z);
            Bs[nl][(scol + 3 - off) & 31] = f2bf(v.w);
        }
        __syncthreads();

        bf16x8 af[4], bfr[4];
#pragma unroll
        for (int m = 0; m < 4; ++m)
            af[m] = *(const bf16x8*)&As[wr * 64 + m * 16 + lrow][lk];
#pragma unroll
        for (int n = 0; n < 4; ++n)
            bfr[n] = *(const bf16x8*)&Bs[wc * 64 + n * 16 + lrow][lk];
#pragma unroll
        for (int m = 0; m < 4; ++m)
#pragma unroll
            for (int n = 0; n < 4; ++n)
                acc[m][n] = __builtin_amdgcn_mfma_f32_16x16x32_bf16(af[m], bfr[n], acc[m][n], 0, 0, 0);
        __syncthreads();
    }

#pragma unroll
    for (int n = 0; n < 4; ++n) {
        const int col = n0 + wc * 64 + n * 16 + lrow;
        const float bv = bias[col];
#pragma unroll
        for (int m = 0; m < 4; ++m) {
            const int rbase = m0 + wr * 64 + m * 16 + (lane >> 4) * 4;
#pragma unroll
            for (int e = 0; e < 4; ++e)
                out[(size_t)(rbase + e) * NDIM + col] = acc[m][n][e] + bv;
        }
    }
}

extern "C" void kernel_launch(void* const* d_in, const int* in_sizes, int n_in,
                              void* d_out, int out_size, void* d_ws, size_t ws_size,
                              hipStream_t stream) {
    const float* x    = (const float*)d_in[0];
    const float* wgt  = (const float*)d_in[1];
    const float* bias = (const float*)d_in[2];
    const int*   rn   = (const int*)d_in[3];
    float* out = (float*)d_out;

    const int M = in_sizes[0] / KDIM;                       // 8192
    const size_t need = ((size_t)M * KDIM + (size_t)NDIM * KDIM) * sizeof(unsigned short);

    if (ws_size >= need && (M % 256) == 0) {
        unsigned short* xb = (unsigned short*)d_ws;
        unsigned short* wx = xb + (size_t)M * KDIM;

        cvt_x<<<2048, 256, 0, stream>>>(x, xb, (long)M * KDIM / 8);
        expand_w<<<2048, 256, 0, stream>>>(wgt, wx, rn);

        const int nwg = (NDIM / 256) * (M / 256);           // 512
        gemm_bt256<<<nwg, 512, 0, stream>>>(xb, wx, bias, out, M);
    } else {
        dim3 grid(NDIM / 128, M / 128);
        ssl_gemm_fused<<<grid, dim3(256), 0, stream>>>(x, wgt, bias, rn, out);
    }
}